// Round 1
// 1733.497 us; speedup vs baseline: 1.1591x; 1.1591x over previous
//
#include <hip/hip_runtime.h>
#include <math.h>

#define B_    32
#define H_    2048
#define V_    128000
#define HIST_ 2048
#define TOPK  50
#define CAP_EQ 8192          // boundary-bin candidate capacity per row (~1.7K expected)
#define NSLICE 16
#define SLICE_ (V_ / NSLICE) // 8000

// ---------------------------------------------------------------- LayerNorm
// Also zeroes the top-k histogram/counter buffers (free: runs long before topk).
__global__ __launch_bounds__(256) void ln_kernel(const float* __restrict__ x,
        const float* __restrict__ gamma, const float* __restrict__ beta,
        float* __restrict__ h, int* __restrict__ ghist, int* __restrict__ meta) {
    int b = blockIdx.x, t = threadIdx.x;
    ghist[b * 256 + t] = 0;
    if (t < 8) meta[b * 8 + t] = 0;
    const float* xr = x + b * H_;
    __shared__ float red[4];
    __shared__ float sval;
    float s = 0.f;
    for (int k = t; k < H_; k += 256) s += xr[k];
    #pragma unroll
    for (int o = 32; o; o >>= 1) s += __shfl_down(s, o);
    if ((t & 63) == 0) red[t >> 6] = s;
    __syncthreads();
    if (t == 0) sval = (red[0] + red[1] + red[2] + red[3]) * (1.f / H_);
    __syncthreads();
    float mu = sval;
    float v = 0.f;
    for (int k = t; k < H_; k += 256) { float d = xr[k] - mu; v += d * d; }
    #pragma unroll
    for (int o = 32; o; o >>= 1) v += __shfl_down(v, o);
    if ((t & 63) == 0) red[t >> 6] = v;
    __syncthreads();
    if (t == 0) sval = 1.f / sqrtf((red[0] + red[1] + red[2] + red[3]) * (1.f / H_) + 1e-5f);
    __syncthreads();
    float rstd = sval;
    for (int k = t; k < H_; k += 256)
        h[b * H_ + k] = (xr[k] - mu) * rstd * gamma[k] + beta[k];
}

// ---------------------------------------------------------------- GEMM
// logits[b][v] = sum_k h[b][k] * W[v][k].  4v x 8b register tile per thread:
// thread (vt = t>>2, bg = (t&3)*8) owns vocab rows {vt, vt+64, vt+128, vt+192}
// (interleaved so row&7 == vt&7 and the XOR swizzle keeps reads 2-way, i.e.
// conflict-free) and batch columns bg..bg+7.  h loads amortize over 4 rows,
// w loads over 8 batches: 96 ds_read_b128 per chunk vs 264 in the 1vx32b
// form — the kernel moves from LDS-issue-bound to HBM-streaming-bound.
#define VT  256   // vocab rows per block
#define KC  32    // k per chunk
#define NCH (H_ / KC)

__global__ __launch_bounds__(256, 2) void gemm_kernel(const float* __restrict__ Wm,
        const float* __restrict__ hs, float* __restrict__ logits) {
    __shared__ float ldsW[VT * KC];   // 32 KB, swizzled
    __shared__ float ldsH[KC * B_];   // 4 KB, transposed h[k][b]
    const int t  = threadIdx.x;
    const int v0 = blockIdx.x * VT;
    const int vt = t >> 2;            // 0..63
    const int bg = (t & 3) * 8;       // batch base: 0,8,16,24

    float acc[4][8];
    #pragma unroll
    for (int r = 0; r < 4; r++)
        #pragma unroll
        for (int j = 0; j < 8; j++) acc[r][j] = 0.f;

    float4 wreg[8];
    float4 hreg;
    const int hb = t >> 3, hk = (t & 7) * 4;

    // preload chunk 0
    #pragma unroll
    for (int i = 0; i < 8; i++) {
        int g = i * 256 + t, r = g >> 3, p = g & 7;
        wreg[i] = *(const float4*)(Wm + (size_t)(v0 + r) * H_ + p * 4);
    }
    hreg = *(const float4*)(hs + hb * H_ + hk);

    for (int c = 0; c < NCH; c++) {
        // stage chunk c into LDS
        #pragma unroll
        for (int i = 0; i < 8; i++) {
            int g = i * 256 + t, r = g >> 3, p = g & 7;
            *(float4*)&ldsW[r * KC + ((p ^ (r & 7)) << 2)] = wreg[i];
        }
        ldsH[(hk + 0) * B_ + hb] = hreg.x;
        ldsH[(hk + 1) * B_ + hb] = hreg.y;
        ldsH[(hk + 2) * B_ + hb] = hreg.z;
        ldsH[(hk + 3) * B_ + hb] = hreg.w;
        __syncthreads();

        // issue prefetch of chunk c+1 (in flight across the compute phase)
        if (c + 1 < NCH) {
            int kn = (c + 1) * KC;
            #pragma unroll
            for (int i = 0; i < 8; i++) {
                int g = i * 256 + t, r = g >> 3, p = g & 7;
                wreg[i] = *(const float4*)(Wm + (size_t)(v0 + r) * H_ + kn + p * 4);
            }
            hreg = *(const float4*)(hs + hb * H_ + kn + hk);
        }

        // compute chunk c
        for (int q = 0; q < KC / 4; q++) {
            const int ws = ((q ^ (vt & 7)) << 2);
            float4 w0 = *(const float4*)&ldsW[(vt      ) * KC + ws];
            float4 w1 = *(const float4*)&ldsW[(vt +  64) * KC + ws];
            float4 w2 = *(const float4*)&ldsW[(vt + 128) * KC + ws];
            float4 w3 = *(const float4*)&ldsW[(vt + 192) * KC + ws];
            #pragma unroll
            for (int j = 0; j < 4; j++) {
                float4 h0 = *(const float4*)&ldsH[(q * 4 + j) * B_ + bg];
                float4 h1 = *(const float4*)&ldsH[(q * 4 + j) * B_ + bg + 4];
                #define STEP(R, W4) { float wv = (&W4.x)[j];                  \
                    acc[R][0] += wv * h0.x; acc[R][1] += wv * h0.y;           \
                    acc[R][2] += wv * h0.z; acc[R][3] += wv * h0.w;           \
                    acc[R][4] += wv * h1.x; acc[R][5] += wv * h1.y;           \
                    acc[R][6] += wv * h1.z; acc[R][7] += wv * h1.w; }
                STEP(0, w0) STEP(1, w1) STEP(2, w2) STEP(3, w3)
                #undef STEP
            }
        }
        __syncthreads();
    }

    // epilogue: per (r,j) a wave writes 4 b-rows x 16 consecutive v (64B segs)
    #pragma unroll
    for (int r = 0; r < 4; r++) {
        int v = v0 + vt + 64 * r;
        #pragma unroll
        for (int j = 0; j < 8; j++)
            logits[(size_t)(bg + j) * V_ + v] = acc[r][j];
    }
}

// ------------------------------------------------------- repetition penalty
__global__ __launch_bounds__(256) void pen_gather(const int* __restrict__ ids,
        const float* __restrict__ logits, float* __restrict__ pen) {
    int i = blockIdx.x * 256 + threadIdx.x;   // < 32*2048
    int b = i >> 11;
    int id = ids[i];
    float g = logits[(size_t)b * V_ + id];
    pen[i] = (g < 0.f) ? g * 1.1f : g / 1.1f;
}
__global__ __launch_bounds__(256) void pen_scatter(const int* __restrict__ ids,
        float* __restrict__ logits, const float* __restrict__ pen) {
    int i = blockIdx.x * 256 + threadIdx.x;
    int b = i >> 11;
    logits[(size_t)b * V_ + ids[i]] = pen[i];
}

// ---------------------------------------------------------------- top-k/top-p
__device__ __forceinline__ unsigned f2k(float f) {
    unsigned u = __float_as_uint(f);
    return (u >> 31) ? ~u : (u | 0x80000000u);   // larger float -> larger key
}
__device__ __forceinline__ float k2f(unsigned k) {
    return __uint_as_float((k >> 31) ? (k ^ 0x80000000u) : ~k);
}

// Pass 1 (32 rows x 16 slices): 8-bit MSB histogram -> global per-row hist.
__global__ __launch_bounds__(256) void topk_hist(const float* __restrict__ logits,
        int* __restrict__ ghist) {
    int row = blockIdx.y, t = threadIdx.x;
    __shared__ int hist[256];
    hist[t] = 0;
    __syncthreads();
    const float4* rp = (const float4*)(logits + (size_t)row * V_);
    int i0 = blockIdx.x * (SLICE_ / 4);
    for (int i = i0 + t; i < i0 + SLICE_ / 4; i += 256) {
        float4 v = rp[i];
        atomicAdd(&hist[f2k(v.x) >> 24], 1);
        atomicAdd(&hist[f2k(v.y) >> 24], 1);
        atomicAdd(&hist[f2k(v.z) >> 24], 1);
        atomicAdd(&hist[f2k(v.w) >> 24], 1);
    }
    __syncthreads();
    if (hist[t]) atomicAdd(&ghist[row * 256 + t], hist[t]);
}

// Pass 2 (32 rows x 16 slices): derive b1 from ghist, collect strict-top
// (byte > b1, count == c1 <= 49 exact) and boundary-bin candidates
// (byte == b1, ~1.7K expected, capped CAP_EQ) to global lists.
__global__ __launch_bounds__(256) void topk_collect(const float* __restrict__ logits,
        const int* __restrict__ ghist, int* __restrict__ meta,
        unsigned* __restrict__ sK, int* __restrict__ sI,
        unsigned* __restrict__ eK, int* __restrict__ eI) {
    int row = blockIdx.y, t = threadIdx.x;
    __shared__ int lh[256];
    __shared__ int sb1;
    lh[t] = ghist[row * 256 + t];
    __syncthreads();
    if (t == 0) {
        int c = 0, i = 255;
        for (; i >= 0; i--) { if (c + lh[i] >= TOPK) break; c += lh[i]; }
        sb1 = i;
    }
    __syncthreads();
    unsigned b1 = (unsigned)sb1;
    const float4* rp = (const float4*)(logits + (size_t)row * V_);
    int i0 = blockIdx.x * (SLICE_ / 4);
    int* nA = &meta[row * 8 + 0];
    int* nE = &meta[row * 8 + 1];
    unsigned* ek = eK + (size_t)row * CAP_EQ;
    int*      ei = eI + (size_t)row * CAP_EQ;
    for (int i = i0 + t; i < i0 + SLICE_ / 4; i += 256) {
        float4 v = rp[i];
        float vv[4] = {v.x, v.y, v.z, v.w};
        #pragma unroll
        for (int u = 0; u < 4; u++) {
            unsigned k = f2k(vv[u]);
            unsigned by = k >> 24;
            if (by >= b1) {
                int idx = i * 4 + u;
                if (by > b1) {
                    int p = atomicAdd(nA, 1);
                    if (p < 64) { sK[row * 64 + p] = k; sI[row * 64 + p] = idx; }
                } else {
                    int p = atomicAdd(nE, 1);
                    if (p < CAP_EQ) { ek[p] = k; ei[p] = idx; }
                }
            }
        }
    }
}

// Pass 3 (32 rows): level-2 refine over the ~1.7K candidate list, exact
// (value desc, idx asc) ordering, then softmax/top-p — identical math to
// the previously-passing kernel, just on a tiny list.
__global__ __launch_bounds__(256) void topk_final(const int* __restrict__ meta,
        const unsigned* __restrict__ sK, const int* __restrict__ sI,
        const unsigned* __restrict__ eK, const int* __restrict__ eI,
        float* __restrict__ out) {
    int row = blockIdx.x, t = threadIdx.x;
    __shared__ int hist[256];
    __shared__ int sb2, scnt, sne2;
    __shared__ unsigned gK[64]; __shared__ int gI[64];
    __shared__ unsigned bK[256]; __shared__ int bI[256];
    __shared__ float outv[TOPK]; __shared__ int outi[TOPK];

    int nA = meta[row * 8 + 0]; if (nA > 64) nA = 64;       // <=49 by construction
    int nE = meta[row * 8 + 1]; if (nE > CAP_EQ) nE = CAP_EQ;

    hist[t] = 0;
    __syncthreads();
    const unsigned* ek = eK + (size_t)row * CAP_EQ;
    const int*      ei = eI + (size_t)row * CAP_EQ;
    for (int i = t; i < nE; i += 256) atomicAdd(&hist[(ek[i] >> 16) & 255], 1);
    __syncthreads();
    if (t == 0) {
        int c = nA, i = 255;
        for (; i >= 0; i--) { if (c + hist[i] >= TOPK) break; c += hist[i]; }
        sb2 = i; scnt = nA; sne2 = 0;
    }
    __syncthreads();
    unsigned b2 = (unsigned)sb2;
    if (t < nA) { gK[t] = sK[row * 64 + t]; gI[t] = sI[row * 64 + t]; }
    for (int i = t; i < nE; i += 256) {
        unsigned by = (ek[i] >> 16) & 255;
        if (by > b2) {
            int p = atomicAdd(&scnt, 1);
            if (p < 64) { gK[p] = ek[i]; gI[p] = ei[i]; }
        } else if (by == b2) {
            int p = atomicAdd(&sne2, 1);
            if (p < 256) { bK[p] = ek[i]; bI[p] = ei[i]; }
        }
    }
    __syncthreads();

    if (t == 0) {
        int na = scnt; if (na > TOPK) na = TOPK;
        // sort strict-top by (key desc, idx asc) — matches lax.top_k stable order
        for (int i = 1; i < na; i++) {
            unsigned k = gK[i]; int id = gI[i]; int j = i - 1;
            for (; j >= 0 && (gK[j] < k || (gK[j] == k && gI[j] > id)); j--) {
                gK[j + 1] = gK[j]; gI[j + 1] = gI[j];
            }
            gK[j + 1] = k; gI[j + 1] = id;
        }
        for (int i = 0; i < na; i++) { outv[i] = k2f(gK[i]); outi[i] = gI[i]; }
        // fill remaining slots from boundary bin by (key desc, idx asc)
        int ne = sne2; if (ne > 256) ne = 256;
        for (int s = na; s < TOPK; s++) {
            int best = -1; unsigned bk = 0; int bi = 0x7fffffff;
            for (int i = 0; i < ne; i++) {
                if (bI[i] < 0) continue;
                if (best < 0 || bK[i] > bk || (bK[i] == bk && bI[i] < bi)) {
                    best = i; bk = bK[i]; bi = bI[i];
                }
            }
            outv[s] = k2f(bk); outi[s] = bi; bI[best] = -1;
        }
    }
    __syncthreads();

    // softmax -> inclusive cumsum -> top-p mask -> softmax, wave-parallel
    if (t < 64) {
        int i = t;
        float m  = outv[0];                                  // sorted desc
        float vi = (i < TOPK) ? outv[i] : 0.f;
        float e  = (i < TOPK) ? expf(vi - m) : 0.f;
        float tot = e;
        #pragma unroll
        for (int o = 1; o < 64; o <<= 1) tot += __shfl_xor(tot, o);
        float p = e / tot;
        float pre = p;                                       // inclusive prefix
        #pragma unroll
        for (int o = 1; o < 64; o <<= 1) { float u = __shfl_up(pre, o); if (t >= o) pre += u; }
        bool keep = (pre < 0.8f) || (i < 5);
        float f  = keep ? vi : -1000.f;
        float e2 = (i < TOPK) ? expf(f - m) : 0.f;
        float tot2 = e2;
        #pragma unroll
        for (int o = 1; o < 64; o <<= 1) tot2 += __shfl_xor(tot2, o);
        if (i < TOPK) {
            out[row * TOPK + i] = e2 / tot2;                 // probs
            out[B_ * TOPK + row * TOPK + i] = (float)outi[i];// tokens as f32
        }
    }
}

// ---------------------------------------------------------------- launch
extern "C" void kernel_launch(void* const* d_in, const int* in_sizes, int n_in,
                              void* d_out, int out_size, void* d_ws, size_t ws_size,
                              hipStream_t stream) {
    const int*   ids    = (const int*)d_in[0];     // input_ids [32,2048]
    const float* hidden = (const float*)d_in[1];   // [32,2048]
    const float* gamma  = (const float*)d_in[2];   // [2048]
    const float* beta   = (const float*)d_in[3];   // [2048]
    const float* Wm     = (const float*)d_in[4];   // [128000,2048]
    float* out = (float*)d_out;

    // workspace layout:
    // h 256KB | logits 16384000B | pen 256KB | ghist 32KB | meta 1KB
    // | sK 8KB | sI 8KB | eK 1MB | eI 1MB   (~19 MB total)
    char* ws = (char*)d_ws;
    size_t off = 0;
    float* h      = (float*)(ws + off); off += 262144;
    float* logits = (float*)(ws + off); off += 16384000;
    float* pen    = (float*)(ws + off); off += 262144;
    int*   ghist  = (int*)  (ws + off); off += 32768;
    int*   meta   = (int*)  (ws + off); off += 1024;
    unsigned* sK  = (unsigned*)(ws + off); off += B_ * 64 * 4;
    int*   sI     = (int*)  (ws + off); off += B_ * 64 * 4;
    unsigned* eK  = (unsigned*)(ws + off); off += (size_t)B_ * CAP_EQ * 4;
    int*   eI     = (int*)  (ws + off); off += (size_t)B_ * CAP_EQ * 4;

    dim3 gslice(NSLICE, B_);

    ln_kernel   <<<B_,        256, 0, stream>>>(hidden, gamma, beta, h, ghist, meta);
    gemm_kernel <<<V_ / VT,   256, 0, stream>>>(Wm, h, logits);
    pen_gather  <<<(B_*HIST_)/256, 256, 0, stream>>>(ids, logits, pen);
    pen_scatter <<<(B_*HIST_)/256, 256, 0, stream>>>(ids, logits, pen);
    topk_hist   <<<gslice,    256, 0, stream>>>(logits, ghist);
    topk_collect<<<gslice,    256, 0, stream>>>(logits, ghist, meta, sK, sI, eK, eI);
    topk_final  <<<B_,        256, 0, stream>>>(meta, sK, sI, eK, eI, out);
}